// Round 1
// 891.393 us; speedup vs baseline: 1.0265x; 1.0265x over previous
//
#include <hip/hip_runtime.h>
#include <math.h>

typedef _Float16 f16;
typedef _Float16 f16x2 __attribute__((ext_vector_type(2)));
typedef _Float16 f16x4 __attribute__((ext_vector_type(4)));
typedef _Float16 f16x8 __attribute__((ext_vector_type(8)));
typedef float f32x4 __attribute__((ext_vector_type(4)));

#define DIVUP(a, b) (((a) + (b) - 1) / (b))

// ---------------- CSR build ----------------

__global__ __launch_bounds__(256) void k_hist(const int* __restrict__ dst, int* __restrict__ deg, int E) {
    int i = blockIdx.x * 256 + threadIdx.x;
    if (i < E) atomicAdd(&deg[dst[i]], 1);
}

__global__ __launch_bounds__(256) void k_scan_block(const int* __restrict__ deg, int* __restrict__ tmp,
                                                    int* __restrict__ bsum, int n) {
    __shared__ int sh[256];
    int i = blockIdx.x * 256 + threadIdx.x;
    int v = (i < n) ? deg[i] : 0;
    sh[threadIdx.x] = v;
    __syncthreads();
    #pragma unroll
    for (int off = 1; off < 256; off <<= 1) {
        int t = (threadIdx.x >= off) ? sh[threadIdx.x - off] : 0;
        __syncthreads();
        sh[threadIdx.x] += t;
        __syncthreads();
    }
    if (i < n) tmp[i] = sh[threadIdx.x];
    if (threadIdx.x == 255) bsum[blockIdx.x] = sh[255];
}

__global__ __launch_bounds__(256) void k_scan_bsum(const int* __restrict__ bsum, int* __restrict__ bsum_ex, int nb) {
    __shared__ int sh[256];
    int t = threadIdx.x;
    int v = (t < nb) ? bsum[t] : 0;
    sh[t] = v;
    __syncthreads();
    #pragma unroll
    for (int off = 1; off < 256; off <<= 1) {
        int u = (t >= off) ? sh[t - off] : 0;
        __syncthreads();
        sh[t] += u;
        __syncthreads();
    }
    bsum_ex[t] = sh[t] - v;  // exclusive
}

__global__ __launch_bounds__(256) void k_scan_finish(const int* __restrict__ tmp, const int* __restrict__ deg,
                                                     const int* __restrict__ bsum_ex, int* __restrict__ offs,
                                                     int* __restrict__ cursor, int n) {
    int i = blockIdx.x * 256 + threadIdx.x;
    if (i < n) {
        int ex = tmp[i] - deg[i] + bsum_ex[blockIdx.x];
        offs[i] = ex;
        cursor[i] = ex;
    }
}

// perm entry: (src, ea_bits, edge_id, unused)
__global__ __launch_bounds__(256) void k_scatter(const int* __restrict__ src, const int* __restrict__ dst,
                                                 const float* __restrict__ ea, int* __restrict__ cursor,
                                                 int4* __restrict__ perm, int E) {
    int i = blockIdx.x * 256 + threadIdx.x;
    if (i < E) {
        int d = dst[i];
        int pos = atomicAdd(&cursor[d], 1);
        perm[pos] = make_int4(src[i], __float_as_int(ea[i]), i, 0);
    }
}

// ---------------- x -> f16 copy (for gather side of aggregation) ----------------
__global__ __launch_bounds__(256) void k_xhalf(const float* __restrict__ x, f16* __restrict__ xh, int n4) {
    int i = blockIdx.x * 256 + threadIdx.x;
    if (i < n4) {
        float4 v = ((const float4*)x)[i];
        f16x4 hv = {(f16)v.x, (f16)v.y, (f16)v.z, (f16)v.w};
        ((f16x4*)xh)[i] = hv;
    }
}

// ---------------- softmax-aggregate + residual (gathers f16 x, writes f16 h) ----------------
__global__ __launch_bounds__(128) void k_aggr_h(const int* __restrict__ offs, const int* __restrict__ deg,
                                                const int4* __restrict__ perm,
                                                const float* __restrict__ x, const f16* __restrict__ xh,
                                                const float* __restrict__ W_edge,
                                                const float* __restrict__ t_ptr, f16* __restrict__ h, int n) {
    int node = blockIdx.x;
    int d = threadIdx.x;
    float t = *t_ptr;
    float we = W_edge[d];
    int start = offs[node], cnt = deg[node];
    float denom = 0.f, numer = 0.f;
    for (int e = 0; e < cnt; ++e) {
        int4 pe = perm[start + e];
        float xv = (float)xh[(size_t)pe.x * 128 + d];
        float ea = __int_as_float(pe.y);
        float m = fmaxf(xv + ea * we, 0.f) + 1e-7f;
        float es = __expf(m * t);
        denom += es;
        numer += m * es;
    }
    h[(size_t)node * 128 + d] = (f16)(numer / (denom + 1e-16f) + x[(size_t)node * 128 + d]);
}

// ---------------- weight prep: fp32 -> f16 (and pack M for edge MLP) ----------------
__global__ __launch_bounds__(256) void k_prep(const float* __restrict__ W1, const float* __restrict__ W2,
                                              const float* __restrict__ We, f16* __restrict__ B1,
                                              f16* __restrict__ B2, f16* __restrict__ BM) {
    int i = blockIdx.x * 256 + threadIdx.x;  // 3*32768
    if (i < 32768) {
        B1[i] = (f16)W1[i];
    } else if (i < 65536) {
        int j = i - 32768;
        B2[j] = (f16)W2[j];
    } else {
        int j = i - 65536;
        int jj = j >> 7, d = j & 127;
        BM[j] = (f16)((jj < 128) ? We[jj * 256 + d] : We[(jj - 128) * 256 + 128 + d]);
    }
}

// ---------------- unified MFMA GEMM: C[n,j] = sum_k A[n,k]*B[j,k] ----------------
// Bg f16 [ncols x KTOT]. 128x128 tile per block, 4 waves of 64x64 via 16x16x32 f16 MFMA.
// LDS stride 136 (f16) keeps frag reads ~2-way.
// MODE 0: A f16, store C f16 (stride 256) + BN column stats (atomics).
// MODE 1: A f16, BN affine+relu fused into A staging, row-LN+ELU epilogue, store fp32 (stride 128).
// MODE 2: A fp32, store C f16 (stride 256).
template <int KTOT, int MODE>
__global__ __launch_bounds__(256) void k_gemm(const void* __restrict__ Av, const f16* __restrict__ Bg,
                                              float* __restrict__ Cout, int nrows,
                                              float* __restrict__ colsum, float* __restrict__ colsq,
                                              const float* __restrict__ bnscale, const float* __restrict__ bnshift,
                                              const float* __restrict__ lng, const float* __restrict__ lnb) {
    __shared__ f16 As[128 * 136];
    __shared__ f16 Bs[128 * 136];
    __shared__ float Ssum[2][128];
    __shared__ float Sq[2][128];
    const int tid = threadIdx.x;
    const int lane = tid & 63, w = tid >> 6;
    const int m = lane & 15, quad = lane >> 4;
    const int row0 = blockIdx.x * 128, col0 = blockIdx.y * 128;
    const int wrow = (w & 1) * 64, wcol = (w >> 1) * 64;
    f32x4 acc[4][4] = {};

    for (int kc = 0; kc < KTOT; kc += 128) {
        if (kc) __syncthreads();
        if (MODE == 2) {
            // stage A (fp32 -> f16)
            const float* A = (const float*)Av;
            #pragma unroll
            for (int q = 0; q < 16; q++) {
                int f = tid + q * 256;
                int r = f >> 5, c4 = f & 31;
                int gr = row0 + r;
                float4 v = (gr < nrows) ? *(const float4*)(A + (size_t)gr * KTOT + kc + c4 * 4)
                                        : make_float4(0.f, 0.f, 0.f, 0.f);
                f16x4 hv = {(f16)v.x, (f16)v.y, (f16)v.z, (f16)v.w};
                *(f16x4*)(As + r * 136 + c4 * 4) = hv;
            }
        } else {
            // stage A (already f16), optional BN+relu (fp32 math on the fly)
            const f16* Ah = (const f16*)Av;
            #pragma unroll
            for (int q = 0; q < 8; q++) {
                int f = tid + q * 256;
                int r = f >> 4, k8 = f & 15;
                int gr = row0 + r;
                f16x8 hv = {};
                if (gr < nrows) hv = *(const f16x8*)(Ah + (size_t)gr * KTOT + kc + k8 * 8);
                if (MODE == 1) {
                    const float* sc = bnscale + kc + k8 * 8;
                    const float* sh = bnshift + kc + k8 * 8;
                    #pragma unroll
                    for (int u = 0; u < 8; u++)
                        hv[u] = (f16)fmaxf(fmaf((float)hv[u], sc[u], sh[u]), 0.f);
                }
                *(f16x8*)(As + r * 136 + k8 * 8) = hv;
            }
        }
        // stage B (already f16)
        #pragma unroll
        for (int q = 0; q < 8; q++) {
            int f = tid + q * 256;
            int r = f >> 4, k8 = f & 15;
            *(uint4*)(Bs + r * 136 + k8 * 8) =
                *(const uint4*)(Bg + (size_t)(col0 + r) * KTOT + kc + k8 * 8);
        }
        __syncthreads();
        #pragma unroll
        for (int k0 = 0; k0 < 128; k0 += 32) {
            f16x8 a[4], b[4];
            #pragma unroll
            for (int i = 0; i < 4; i++)
                a[i] = *(const f16x8*)(As + (wrow + i * 16 + m) * 136 + k0 + quad * 8);
            #pragma unroll
            for (int j = 0; j < 4; j++)
                b[j] = *(const f16x8*)(Bs + (wcol + j * 16 + m) * 136 + k0 + quad * 8);
            #pragma unroll
            for (int i = 0; i < 4; i++)
                #pragma unroll
                for (int j = 0; j < 4; j++)
                    acc[i][j] = __builtin_amdgcn_mfma_f32_16x16x32_f16(a[i], b[j], acc[i][j], 0, 0, 0);
        }
    }

    if (MODE == 0 || MODE == 2) {
        f16* Ch = (f16*)Cout;
        #pragma unroll
        for (int i = 0; i < 4; i++)
            #pragma unroll
            for (int r = 0; r < 4; r++) {
                int grow = row0 + wrow + i * 16 + quad * 4 + r;
                if (grow < nrows) {
                    #pragma unroll
                    for (int j = 0; j < 4; j++)
                        Ch[(size_t)grow * 256 + col0 + wcol + j * 16 + m] = (f16)acc[i][j][r];
                }
            }
    }
    if (MODE == 0) {
        // BN column stats: per-lane partial over its 16 rows, xor-16/32 reduce across quads,
        // lanes 0..15 hold 64-row totals for this wave -> global atomics.
        #pragma unroll
        for (int j = 0; j < 4; j++) {
            float s = 0.f, qq = 0.f;
            #pragma unroll
            for (int i = 0; i < 4; i++)
                #pragma unroll
                for (int r = 0; r < 4; r++) {
                    float v = acc[i][j][r];
                    s += v;
                    qq += v * v;
                }
            s += __shfl_xor(s, 16); s += __shfl_xor(s, 32);
            qq += __shfl_xor(qq, 16); qq += __shfl_xor(qq, 32);
            if (lane < 16) {
                atomicAdd(&colsum[col0 + wcol + j * 16 + lane], s);
                atomicAdd(&colsq[col0 + wcol + j * 16 + lane], qq);
            }
        }
    }
    if (MODE == 1) {
        // row-LN over 128 cols + ELU. xor 1/2/4/8 reduce within quads (64 cols per wave),
        // cross-col-wave combine via tiny LDS arrays.
        const int cw = w >> 1;
        #pragma unroll
        for (int i = 0; i < 4; i++)
            #pragma unroll
            for (int r = 0; r < 4; r++) {
                float s = 0.f, qq = 0.f;
                #pragma unroll
                for (int j = 0; j < 4; j++) {
                    float v = acc[i][j][r];
                    s += v;
                    qq += v * v;
                }
                s += __shfl_xor(s, 1); s += __shfl_xor(s, 2);
                s += __shfl_xor(s, 4); s += __shfl_xor(s, 8);
                qq += __shfl_xor(qq, 1); qq += __shfl_xor(qq, 2);
                qq += __shfl_xor(qq, 4); qq += __shfl_xor(qq, 8);
                if (m == 0) {
                    int lrow = wrow + i * 16 + quad * 4 + r;
                    Ssum[cw][lrow] = s;
                    Sq[cw][lrow] = qq;
                }
            }
        __syncthreads();
        float lg[4], lb[4];
        #pragma unroll
        for (int j = 0; j < 4; j++) {
            lg[j] = lng[wcol + j * 16 + m];
            lb[j] = lnb[wcol + j * 16 + m];
        }
        #pragma unroll
        for (int i = 0; i < 4; i++)
            #pragma unroll
            for (int r = 0; r < 4; r++) {
                int lrow = wrow + i * 16 + quad * 4 + r;
                int grow = row0 + lrow;
                if (grow < nrows) {
                    float S = Ssum[0][lrow] + Ssum[1][lrow];
                    float Q = Sq[0][lrow] + Sq[1][lrow];
                    float mu = S * (1.f / 128.f);
                    float var = Q * (1.f / 128.f) - mu * mu;
                    float rs = rsqrtf(var + 1e-5f);
                    #pragma unroll
                    for (int j = 0; j < 4; j++) {
                        float v = (acc[i][j][r] - mu) * rs * lg[j] + lb[j];
                        v = v > 0.f ? v : expm1f(v);
                        Cout[(size_t)grow * 128 + wcol + j * 16 + m] = v;
                    }
                }
            }
    }
}

__global__ __launch_bounds__(256) void k_bn_finish(const float* __restrict__ colsum, const float* __restrict__ colsq,
                                                   const float* __restrict__ g, const float* __restrict__ b,
                                                   float* __restrict__ scale, float* __restrict__ shift, float invN) {
    int j = threadIdx.x;  // 256
    float mu = colsum[j] * invN;
    float var = colsq[j] * invN - mu * mu;
    float sc = g[j] * rsqrtf(var + 1e-5f);
    scale[j] = sc;
    shift[j] = b[j] - mu * sc;
}

// ---------------- edge output: CSR-ordered, wave per destination node ----------------
// vb half (dst) hoisted into registers once per node; only src half gathered (f16).
// Writes out_e rows at original edge positions via eid stored in perm.
__global__ __launch_bounds__(256) void k_edge_out(const int* __restrict__ offs, const int* __restrict__ deg,
                                                  const int4* __restrict__ perm, const f16* __restrict__ CAB,
                                                  const float* __restrict__ be,
                                                  const float* __restrict__ lng, const float* __restrict__ lnb,
                                                  float* __restrict__ oute, int N) {
    int node = blockIdx.x * 4 + (threadIdx.x >> 6);
    int lane = threadIdx.x & 63;
    if (node >= N) return;
    int cnt = deg[node];
    if (cnt == 0) return;
    int start = offs[node];
    int k = lane * 2;
    f16x2 vb = *(const f16x2*)(CAB + (size_t)node * 256 + 128 + k);
    float2 bb = *(const float2*)(be + k);
    float bx = (float)vb.x + bb.x;
    float by = (float)vb.y + bb.y;
    float2 gg = *(const float2*)(lng + k);
    float2 b2 = *(const float2*)(lnb + k);
    const float is2 = 0.70710678118654752f;

    int4 pe = perm[start];
    for (int e = 0; e < cnt; ++e) {
        int4 pen = (e + 1 < cnt) ? perm[start + e + 1] : pe;  // prefetch next entry
        f16x2 va = *(const f16x2*)(CAB + (size_t)pe.x * 256 + k);
        float x0 = (float)va.x + bx;
        float x1 = (float)va.y + by;
        float g0 = 0.5f * x0 * (1.f + erff(x0 * is2));
        float g1 = 0.5f * x1 * (1.f + erff(x1 * is2));
        float s1 = g0 + g1, s2 = g0 * g0 + g1 * g1;
        #pragma unroll
        for (int off = 32; off; off >>= 1) {
            s1 += __shfl_xor(s1, off);
            s2 += __shfl_xor(s2, off);
        }
        float mu = s1 * (1.f / 128.f);
        float var = s2 * (1.f / 128.f) - mu * mu;
        float rs = rsqrtf(var + 1e-5f);
        float o0 = (g0 - mu) * rs * gg.x + b2.x;
        float o1 = (g1 - mu) * rs * gg.y + b2.y;
        *(float2*)(oute + (size_t)pe.z * 128 + k) = make_float2(o0, o1);
        pe = pen;
    }
}

extern "C" void kernel_launch(void* const* d_in, const int* in_sizes, int n_in,
                              void* d_out, int out_size, void* d_ws, size_t ws_size,
                              hipStream_t stream) {
    const int N = in_sizes[0] / 128;  // 50000
    const int E = in_sizes[1] / 2;    // 800000

    const float* x      = (const float*)d_in[0];
    const int*   ei     = (const int*)d_in[1];
    const int*   src    = ei;
    const int*   dst    = ei + E;
    const float* ea     = (const float*)d_in[2];
    const float* W_edge = (const float*)d_in[3];
    const float* t_ptr  = (const float*)d_in[4];
    const float* W1     = (const float*)d_in[5];
    const float* bng    = (const float*)d_in[6];
    const float* bnb    = (const float*)d_in[7];
    const float* W2     = (const float*)d_in[8];
    const float* lng    = (const float*)d_in[9];
    const float* lnb    = (const float*)d_in[10];
    const float* We     = (const float*)d_in[11];
    const float* be     = (const float*)d_in[12];
    const float* lneg   = (const float*)d_in[13];
    const float* lneb   = (const float*)d_in[14];

    float* out_x = (float*)d_out;                      // [N,128]
    float* out_e = out_x + (size_t)N * 128;            // [E,128]

    // ---- workspace layout (all f16 intermediates) ----
    f16*   h   = (f16*)d_ws;                           // N*128 f16
    f16*   xh  = h + (size_t)N * 128;                  // N*128 f16
    f16*   C   = xh + (size_t)N * 128;                 // N*256 f16 (h1, later C_AB)
    int4*  perm    = (int4*)(C + (size_t)N * 256);     // E (src, ea-bits, eid, 0) — lives until edge_out
    int*   deg     = (int*)(perm + E);                 // N
    int*   offs    = deg + N;                          // N
    int*   cursor  = offs + N;                         // N
    int*   tmp     = cursor + N;                       // N
    int*   bsum    = tmp + N;                          // 256
    int*   bsum_ex = bsum + 256;                       // 256
    float* small   = (float*)(bsum_ex + 256);
    float* colsum  = small;                            // 256
    float* colsq   = small + 256;                      // 256
    float* bnscale = small + 512;                      // 256
    float* bnshift = small + 768;                      // 256
    f16*   B1f16   = (f16*)(small + 1024);             // 256*128
    f16*   B2f16   = B1f16 + 32768;                    // 128*256
    f16*   BMf16   = B2f16 + 32768;                    // 256*128

    const int EB = DIVUP(E, 256);
    const int NB = DIVUP(N, 256);
    const int GR = DIVUP(N, 128);

    hipMemsetAsync(deg, 0, (size_t)N * sizeof(int), stream);
    hipMemsetAsync(colsum, 0, 512 * sizeof(float), stream);

    // weight prep + x->f16 (independent of graph work)
    k_prep<<<384, 256, 0, stream>>>(W1, W2, We, B1f16, B2f16, BMf16);
    k_xhalf<<<DIVUP(N * 32, 256), 256, 0, stream>>>(x, xh, N * 32);

    // CSR build
    k_hist<<<EB, 256, 0, stream>>>(dst, deg, E);
    k_scan_block<<<NB, 256, 0, stream>>>(deg, tmp, bsum, N);
    k_scan_bsum<<<1, 256, 0, stream>>>(bsum, bsum_ex, NB);
    k_scan_finish<<<NB, 256, 0, stream>>>(tmp, deg, bsum_ex, offs, cursor, N);
    k_scatter<<<EB, 256, 0, stream>>>(src, dst, ea, cursor, perm, E);

    // GENConv aggregate + residual (f16 gather, f16 h out)
    k_aggr_h<<<N, 128, 0, stream>>>(offs, deg, perm, x, xh, W_edge, t_ptr, h, N);

    // MLP (f16 MFMA)
    k_gemm<128, 0><<<dim3(GR, 2), 256, 0, stream>>>(h, B1f16, (float*)C, N, colsum, colsq,
                                                    nullptr, nullptr, nullptr, nullptr);
    k_bn_finish<<<1, 256, 0, stream>>>(colsum, colsq, bng, bnb, bnscale, bnshift, 1.0f / (float)N);
    k_gemm<256, 1><<<dim3(GR, 1), 256, 0, stream>>>(C, B2f16, out_x, N, nullptr, nullptr,
                                                    bnscale, bnshift, lng, lnb);

    // edge MLP (factorized per-node), C_AB stored f16
    k_gemm<128, 2><<<dim3(GR, 2), 256, 0, stream>>>(out_x, BMf16, (float*)C, N, nullptr, nullptr,
                                                    nullptr, nullptr, nullptr, nullptr);
    k_edge_out<<<DIVUP(N, 4), 256, 0, stream>>>(offs, deg, perm, C, be, lneg, lneb, out_e, E > 0 ? N : 0);
}